// Round 7
// baseline (8170.582 us; speedup 1.0000x reference)
//
#include <hip/hip_runtime.h>

// Dims
constexpr int TSTEPS = 512;
constexpr int FDIM   = 128;
constexpr int HDIM   = 256;
constexpr int G4H    = 1024;   // 4*H
constexpr int BATCH  = 256;
constexpr int NB     = 86;     // 84 blocks x 3 rows + 2 x 2 rows
constexpr int NKP    = 192;    // merged k-pairs: kp<128 rker, kp>=128 kern

typedef float    f32x2 __attribute__((ext_vector_type(2)));
typedef float    f32x4 __attribute__((ext_vector_type(4)));
typedef _Float16 h2    __attribute__((ext_vector_type(2)));
typedef _Float16 f16x8 __attribute__((ext_vector_type(8)));
typedef unsigned int u32;

#if defined(__has_builtin)
#if __has_builtin(__builtin_amdgcn_fdot2)
#define FDOT2(a, b, c) __builtin_amdgcn_fdot2((a), (b), (c), false)
#endif
#endif
#ifndef FDOT2
#define FDOT2(a, b, c) ((c) + (float)(a)[0] * (float)(b)[0] + (float)(a)[1] * (float)(b)[1])
#endif

__device__ __forceinline__ float sigmf(float z) { return 1.f / (1.f + __expf(-z)); }
__device__ __forceinline__ float tanhf_fast(float z) {
    float a = fabsf(z);
    float e = __expf(-2.f * a);
    float r = (1.f - e) / (1.f + e);
    return z < 0.f ? -r : r;
}

// Repack weights to fp16 k-pairs: wpk[kp][c] = (w[2kp][c], w[2kp+1][c]).
// kp<128 from rker (k=0..255), kp>=128 from kern (k=0..127 of F). 768 KB.
extern "C" __global__ void __launch_bounds__(256)
conv_wpk(const float* __restrict__ kern, const float* __restrict__ rker,
         u32* __restrict__ wpk)
{
    for (int i = blockIdx.x * 256 + threadIdx.x; i < NKP * G4H; i += gridDim.x * 256) {
        const int kp = i >> 10, c = i & 1023;
        float a, b;
        if (kp < 128) {
            a = rker[(size_t)(2 * kp) * G4H + c];
            b = rker[(size_t)(2 * kp + 1) * G4H + c];
        } else {
            const int k0 = (kp - 128) * 2;
            a = kern[(size_t)k0 * G4H + c];
            b = kern[(size_t)(k0 + 1) * G4H + c];
        }
        union { h2 p; u32 u; } cv;
        cv.p = h2{(_Float16)a, (_Float16)b};
        wpk[i] = cv.u;
    }
}

// Zero-sync LSTM, dot2 + TRUE VGPR-resident rker half.
// Round-6 failure: 1024-thr blocks cap VGPRs at 64..128 -> wres spilled to
// scratch (FETCH 7.7 GB). Fix: 512 threads, __launch_bounds__(512,2) -> 256-reg
// cap, 8 waves/CU. wres[32] (128 regs) holds 32 of the 64 rker kp per thread:
// 256 KB/block resident; streamed/step = 256 KB rker + 256 KB kern = 512 KB
// -> port ~8.5k cyc; VALU ~6k cyc overlapped under it.
// Wave roles: khalf = wave>>2 (K split), gate = wave&3; lane owns 4 cols.
extern "C" __global__ void __launch_bounds__(512, 2)
lstm_res(const float* __restrict__ x, const u32* __restrict__ wpk,
         const float* __restrict__ w1, const float* __restrict__ b1,
         const float* __restrict__ w2, const float* __restrict__ b2,
         float* __restrict__ out)
{
    const int b    = blockIdx.x;
    const int base = (b < 84) ? 3 * b : 252 + 2 * (b - 84);
    const int nval = (b < 84) ? 3 : 2;
    const int tid  = threadIdx.x;
    const int wave = tid >> 6;
    const int lane = tid & 63;
    const int kh   = wave >> 2;               // K half
    const int gate = wave & 3;
    const int coff = gate * 256 + lane * 4;   // 4 consecutive columns

    __shared__ __align__(16) u32   hx[NKP * 4];   // [kp][row] fp16 pairs; kp<128 h, >=128 x
    __shared__ __align__(16) float zp[2][3][G4H]; // half partials, 24 KB
    __shared__ float hid[3][104];

    // h(0) = 0 (kp<128 region = 512 u32; all 512 threads)
    hx[tid] = 0;

    const u32* wp = wpk + coff;

    // ---- Resident rker: kp in [64kh, 64kh+32) -> 128 VGPRs/thread, 256 KB/block
    f16x8 wres[32];
#pragma unroll
    for (int i = 0; i < 32; ++i)
        wres[i] = *reinterpret_cast<const f16x8*>(wp + (size_t)(kh * 64 + i) * G4H);

    // Streamed kp index map: i<32 -> rker [64kh+32+i]; i>=32 -> kern [96+32kh+i]
#define KPS(i) ((i) < 32 ? (kh * 64 + 32 + (i)) : (96 + kh * 32 + (i)))

    float cstA = 0.f, cstB = 0.f;
    const int rA = tid >> 8, uA = tid & 255;  // P2 cell A; cell B = (2, tid) for tid<256

    // x staging: tid<192 -> row = tid>>6, fp = tid&63 (8B loads, coalesced per row)
    const int xrow = tid >> 6, xfp = tid & 63;
    const float* xp = x + ((size_t)min(base + xrow, BATCH - 1) * TSTEPS) * FDIM + 2 * xfp;

#pragma unroll 1
    for (int t = 0; t < TSTEPS; ++t) {
        // ---- Prefetch ring head BEFORE the barrier (in flight across B1)
        f16x8 pf[4];
#pragma unroll
        for (int j = 0; j < 4; ++j)
            pf[j] = *reinterpret_cast<const f16x8*>(wp + (size_t)KPS(j) * G4H);

        // ---- Stage x(t) as fp16 pairs -> hx[128+fp][row]
        if (tid < 192) {
            const f32x2 xv = *reinterpret_cast<const f32x2*>(xp + (size_t)t * FDIM);
            union { h2 p; u32 u; } cv;
            cv.p = h2{(_Float16)xv[0], (_Float16)xv[1]};
            hx[(128 + xfp) * 4 + xrow] = cv.u;
        }
        __syncthreads();  // B1: x+h staged; zp(t-1) consumed

        float acc[3][4];
#pragma unroll
        for (int r = 0; r < 3; ++r)
#pragma unroll
            for (int j = 0; j < 4; ++j) acc[r][j] = 0.f;

        // ---- Streamed 64 kp (32 rker + 32 kern), rotating 4-deep prefetch
#pragma unroll
        for (int i = 0; i < 64; ++i) {
            const f16x8 W = pf[i & 3];
            if (i < 60)
                pf[i & 3] = *reinterpret_cast<const f16x8*>(wp + (size_t)KPS(i + 4) * G4H);
            const f16x8 H = *reinterpret_cast<const f16x8*>(&hx[KPS(i) * 4]);
            const h2 h0 = {H[0], H[1]}, h1v = {H[2], H[3]}, h2v = {H[4], H[5]};
#pragma unroll
            for (int j = 0; j < 4; ++j) {
                const h2 wj = {W[2 * j], W[2 * j + 1]};
                acc[0][j] = FDOT2(wj, h0, acc[0][j]);
                acc[1][j] = FDOT2(wj, h1v, acc[1][j]);
                acc[2][j] = FDOT2(wj, h2v, acc[2][j]);
            }
        }
        // ---- Resident 32 kp (no VMEM)
#pragma unroll
        for (int i = 0; i < 32; ++i) {
            const f16x8 W = wres[i];
            const f16x8 H = *reinterpret_cast<const f16x8*>(&hx[(kh * 64 + i) * 4]);
            const h2 h0 = {H[0], H[1]}, h1v = {H[2], H[3]}, h2v = {H[4], H[5]};
#pragma unroll
            for (int j = 0; j < 4; ++j) {
                const h2 wj = {W[2 * j], W[2 * j + 1]};
                acc[0][j] = FDOT2(wj, h0, acc[0][j]);
                acc[1][j] = FDOT2(wj, h1v, acc[1][j]);
                acc[2][j] = FDOT2(wj, h2v, acc[2][j]);
            }
        }

        // ---- Partials: lane-consecutive b128 stores, conflict-free
#pragma unroll
        for (int r = 0; r < 3; ++r)
            *reinterpret_cast<f32x4*>(&zp[kh][r][coff]) =
                f32x4{acc[r][0], acc[r][1], acc[r][2], acc[r][3]};
        __syncthreads();  // B2

        // ---- P2: combine halves, gates, cell update, h(t+1) -> hx (fp16 half-writes)
        {
            const float z0 = zp[0][rA][0 * 256 + uA] + zp[1][rA][0 * 256 + uA];
            const float z1 = zp[0][rA][1 * 256 + uA] + zp[1][rA][1 * 256 + uA];
            const float z2 = zp[0][rA][2 * 256 + uA] + zp[1][rA][2 * 256 + uA];
            const float z3 = zp[0][rA][3 * 256 + uA] + zp[1][rA][3 * 256 + uA];
            cstA = sigmf(z1) * cstA + sigmf(z0) * tanhf_fast(z2);
            const float hnew = sigmf(z3) * tanhf_fast(cstA);
            ((_Float16*)hx)[((uA >> 1) * 4 + rA) * 2 + (uA & 1)] = (_Float16)hnew;
        }
        if (tid < 256) {
            const float z0 = zp[0][2][0 * 256 + tid] + zp[1][2][0 * 256 + tid];
            const float z1 = zp[0][2][1 * 256 + tid] + zp[1][2][1 * 256 + tid];
            const float z2 = zp[0][2][2 * 256 + tid] + zp[1][2][2 * 256 + tid];
            const float z3 = zp[0][2][3 * 256 + tid] + zp[1][2][3 * 256 + tid];
            cstB = sigmf(z1) * cstB + sigmf(z0) * tanhf_fast(z2);
            const float hnew = sigmf(z3) * tanhf_fast(cstB);
            ((_Float16*)hx)[((tid >> 1) * 4 + 2) * 2 + (tid & 1)] = (_Float16)hnew;
        }
        // No barrier: B1(next) orders hx writes / zp reuse.
    }
    __syncthreads();

    // ---- Fused head: out[row] = relu(h@w1+b1)@w2 + b2 (h fp16 from hx)
    if (tid < 300) {
        const int r = tid / 100, j = tid - r * 100;
        if (r < nval) {
            float a = b1[j];
            const _Float16* hph = (const _Float16*)hx;
#pragma unroll 8
            for (int k = 0; k < HDIM; ++k)
                a += (float)hph[(k >> 1) * 8 + r * 2 + (k & 1)] * w1[k * 100 + j];
            hid[r][j] = fmaxf(a, 0.f);
        }
    }
    __syncthreads();
    if (tid < 3 && tid < nval) {
        float v = b2[0];
#pragma unroll 4
        for (int j = 0; j < 100; ++j) v += hid[tid][j] * w2[j];
        out[base + tid] = v;
    }
#undef KPS
}

extern "C" void kernel_launch(void* const* d_in, const int* in_sizes, int n_in,
                              void* d_out, int out_size, void* d_ws, size_t ws_size,
                              hipStream_t stream)
{
    const float* x    = (const float*)d_in[0];
    const float* kern = (const float*)d_in[1];
    const float* rker = (const float*)d_in[2];
    const float* w1   = (const float*)d_in[3];
    const float* b1   = (const float*)d_in[4];
    const float* w2   = (const float*)d_in[5];
    const float* b2   = (const float*)d_in[6];
    float* out = (float*)d_out;

    u32* wpk = (u32*)d_ws;  // 768 KB (ws_size >= 768 KB proven: rounds 5-6 ran this)

    conv_wpk<<<dim3(768), dim3(256), 0, stream>>>(kern, rker, wpk);
    lstm_res<<<dim3(NB), dim3(512), 0, stream>>>(x, wpk, w1, b1, w2, b2, out);
}

// Round 8
// 5237.417 us; speedup vs baseline: 1.5600x; 1.5600x over previous
//
#include <hip/hip_runtime.h>

// Dims
constexpr int TSTEPS = 512;
constexpr int FDIM   = 128;
constexpr int HDIM   = 256;
constexpr int G4H    = 1024;   // 4*H
constexpr int BATCH  = 256;
constexpr int NB     = 86;     // 84 blocks x 3 rows + 2 x 2 rows
constexpr int NKP    = 192;    // wpk k-pairs: kp<128 rker, kp in [128,192) kern
constexpr int TC     = 8;      // time-chunk (xz precompute granularity)
constexpr int NCH    = TSTEPS / TC;

typedef float        f32x2 __attribute__((ext_vector_type(2)));
typedef _Float16     h2    __attribute__((ext_vector_type(2)));
typedef unsigned int u32;
typedef u32          u32x2 __attribute__((ext_vector_type(2)));
typedef u32          u32x4 __attribute__((ext_vector_type(4)));

#if defined(__has_builtin)
#if __has_builtin(__builtin_amdgcn_fdot2)
#define FDOT2(a, b, c) __builtin_amdgcn_fdot2((a), (b), (c), false)
#endif
#endif
#ifndef FDOT2
#define FDOT2(a, b, c) ((c) + (float)(a)[0] * (float)(b)[0] + (float)(a)[1] * (float)(b)[1])
#endif

__device__ __forceinline__ h2 as_h2(u32 v) { union { u32 u; h2 p; } c; c.u = v; return c.p; }
__device__ __forceinline__ u32 pack_h2(float a, float b) {
    union { h2 p; u32 u; } c; c.p = h2{(_Float16)a, (_Float16)b}; return c.u;
}
__device__ __forceinline__ float sigmf(float z) { return 1.f / (1.f + __expf(-z)); }
__device__ __forceinline__ float tanhf_fast(float z) {
    float a = fabsf(z);
    float e = __expf(-2.f * a);
    float r = (1.f - e) / (1.f + e);
    return z < 0.f ? -r : r;
}

// Repack weights to fp16 k-pairs: wpk[kp*1024 + c] = (w[2kp][c], w[2kp+1][c]).
// kp<128 from rker, kp>=128 from kern. 768 KB (ws_size >= 768 KB proven r5-7).
extern "C" __global__ void __launch_bounds__(256)
conv_wpk(const float* __restrict__ kern, const float* __restrict__ rker,
         u32* __restrict__ wpk)
{
    for (int i = blockIdx.x * 256 + threadIdx.x; i < NKP * G4H; i += gridDim.x * 256) {
        const int kp = i >> 10, c = i & 1023;
        float a, b;
        if (kp < 128) {
            a = rker[(size_t)(2 * kp) * G4H + c];
            b = rker[(size_t)(2 * kp + 1) * G4H + c];
        } else {
            const int k0 = (kp - 128) * 2;
            a = kern[(size_t)k0 * G4H + c];
            b = kern[(size_t)(k0 + 1) * G4H + c];
        }
        wpk[i] = pack_h2(a, b);
    }
}

// Zero-sync LSTM with chunked xz-precompute.
// r4-7 established: per-CU load port (~60 B/cyc) x streamed-bytes/step is the
// floor; VGPR weight residency is compiler-blocked (spills at >128 regs).
// This round: kern leaves the recurrent loop entirely (xz = x@kern computed
// per 8-step chunk into LDS; kern streamed once/chunk = 32 KB/step amortized).
// Recurrent loop streams rker fp16 only: 512 KB/step -> 8.5k cyc -> 3.56 us.
// 86 blocks x 512 thr; wave=(gate,colhalf), lane owns 2 cols, full K=128
// pairs/thread -> thread owns final z (no cross-wave reduce). Small reg arrays
// only (ring-8 prefetch, acc[24] f32x2) -> ~90 VGPRs, no spill.
extern "C" __global__ void __launch_bounds__(512)
lstm_chunk(const float* __restrict__ x, const u32* __restrict__ wpk,
           const float* __restrict__ w1, const float* __restrict__ b1,
           const float* __restrict__ w2, const float* __restrict__ b2,
           float* __restrict__ out)
{
    const int b    = blockIdx.x;
    const int base = (b < 84) ? 3 * b : 252 + 2 * (b - 84);
    const int nval = (b < 84) ? 3 : 2;
    const int tid  = threadIdx.x;
    const int wave = tid >> 6;
    const int lane = tid & 63;

    // LDS budget 64688 B <= 64 KB
    __shared__ __align__(16) u32   xzu[TC * 3 * 512];  // 48 KB: xz fp16 pairs [(tc*3+r)*512 + c2]
    __shared__ __align__(16) float ovl[3 * G4H];       // 12 KB: phase A = x16 (first 6 KB) / phase B = zfin
    __shared__ __align__(16) u32   hpk[128 * 4];       // 2 KB: h fp16 pairs [kp][row(4)]
    __shared__ float hid[3][100];                      // 1.2 KB: head hidden

    u32* x16u = (u32*)ovl;  // phase-A x staging: [rt(24)][fp(64)] fp16 pairs

    hpk[tid] = 0;  // h(0) = 0 (512 entries; ordered vs first use by chunk barriers)

    // Phase-B wave mapping: gate g, column half ch; lane owns 2 cols
    const int g    = wave & 3;
    const int ch   = wave >> 2;
    const int cc0  = g * 256 + ch * 128 + 2 * lane;
    const u32* wb  = wpk + cc0;          // rker pair row kp at wb + kp*1024

    // P2 mapping: cell A = (row rA, unit uA) all threads; cell B = (row 2, tid) for tid<256
    const int rA = tid >> 8, uA = tid & 255;
    float cstA = 0.f, cstB = 0.f;

#pragma unroll 1
    for (int chnk = 0; chnk < NCH; ++chnk) {
        __syncthreads();  // A0: prev-chunk P2 (zfin/xzu reads, hpk writes) done

        // ---- Stage x chunk -> x16u[rt][fp], rt = t*3+r (1536 pair-slots, 3/thread)
#pragma unroll
        for (int i = 0; i < 3; ++i) {
            const int idx = tid + i * 512;
            const int rt = idx >> 6, fp = idx & 63;
            const int tt = rt / 3, rr = rt - 3 * tt;
            const int row = min(base + rr, BATCH - 1);
            const f32x2 xv = *reinterpret_cast<const f32x2*>(
                x + ((size_t)row * TSTEPS + (chnk * TC + tt)) * FDIM + 2 * fp);
            x16u[idx] = pack_h2(xv[0], xv[1]);
        }
        __syncthreads();  // A1: x16 ready

        // ---- Phase A: xz[rt][2 cols of this thread] = sum_kp kern-pair . x-pair
        // Thread owns cols (2*tid, 2*tid+1). W ring: 2 groups x 4 kp (16 regs).
        {
            f32x2 acc[24];
#pragma unroll
            for (int rt = 0; rt < 24; ++rt) acc[rt] = f32x2{0.f, 0.f};

            u32x2 Wc0[4], Wc1[4];
#pragma unroll
            for (int q = 0; q < 4; ++q)
                Wc0[q] = *reinterpret_cast<const u32x2*>(&wpk[(size_t)(128 + q) * G4H + 2 * tid]);

            for (int g2 = 0; g2 < 16; g2 += 2) {
                // body even: use Wc0, prefetch grp g2+1 into Wc1
#pragma unroll
                for (int q = 0; q < 4; ++q)
                    Wc1[q] = *reinterpret_cast<const u32x2*>(
                        &wpk[(size_t)(128 + 4 * (g2 + 1) + q) * G4H + 2 * tid]);
#pragma unroll
                for (int rt = 0; rt < 24; ++rt) {
                    const u32x4 X = *reinterpret_cast<const u32x4*>(&x16u[rt * 64 + 4 * g2]);
#pragma unroll
                    for (int q = 0; q < 4; ++q) {
                        const h2 xp = as_h2(X[q]);
                        acc[rt][0] = FDOT2(as_h2(Wc0[q][0]), xp, acc[rt][0]);
                        acc[rt][1] = FDOT2(as_h2(Wc0[q][1]), xp, acc[rt][1]);
                    }
                }
                // body odd: use Wc1, prefetch grp g2+2 into Wc0
                if (g2 + 2 < 16) {
#pragma unroll
                    for (int q = 0; q < 4; ++q)
                        Wc0[q] = *reinterpret_cast<const u32x2*>(
                            &wpk[(size_t)(128 + 4 * (g2 + 2) + q) * G4H + 2 * tid]);
                }
#pragma unroll
                for (int rt = 0; rt < 24; ++rt) {
                    const u32x4 X = *reinterpret_cast<const u32x4*>(&x16u[rt * 64 + 4 * (g2 + 1)]);
#pragma unroll
                    for (int q = 0; q < 4; ++q) {
                        const h2 xp = as_h2(X[q]);
                        acc[rt][0] = FDOT2(as_h2(Wc1[q][0]), xp, acc[rt][0]);
                        acc[rt][1] = FDOT2(as_h2(Wc1[q][1]), xp, acc[rt][1]);
                    }
                }
            }
#pragma unroll
            for (int rt = 0; rt < 24; ++rt)
                xzu[rt * 512 + tid] = pack_h2(acc[rt][0], acc[rt][1]);
        }
        // (no barrier needed here: T1 of step 0 orders xzu/x16u vs consumers)

        // ---- Phase B: 8 recurrence steps, rker-only stream
#pragma unroll 1
        for (int tc = 0; tc < TC; ++tc) {
            // Prefetch ring head before the barrier (lands during barrier wait)
            u32x2 pf[8];
#pragma unroll
            for (int j = 0; j < 8; ++j)
                pf[j] = *reinterpret_cast<const u32x2*>(wb + (size_t)j * G4H);

            __syncthreads();  // T1: hpk(t) ready; zfin(prev) consumed; xz ready (step 0)

            f32x2 a0 = {0.f, 0.f}, a1 = a0, a2 = a0;
#pragma unroll
            for (int kp = 0; kp < 128; ++kp) {
                const u32x2 W = pf[kp & 7];
                if (kp < 120)
                    pf[kp & 7] = *reinterpret_cast<const u32x2*>(wb + (size_t)(kp + 8) * G4H);
                const u32x4 H = *reinterpret_cast<const u32x4*>(&hpk[kp * 4]);  // broadcast
                const h2 h0 = as_h2(H[0]), h1 = as_h2(H[1]), hr2 = as_h2(H[2]);
                const h2 w0 = as_h2(W[0]), w1h = as_h2(W[1]);
                a0[0] = FDOT2(w0, h0, a0[0]);  a0[1] = FDOT2(w1h, h0, a0[1]);
                a1[0] = FDOT2(w0, h1, a1[0]);  a1[1] = FDOT2(w1h, h1, a1[1]);
                a2[0] = FDOT2(w0, hr2, a2[0]); a2[1] = FDOT2(w1h, hr2, a2[1]);
            }
            // zfin: thread owns final z for its 2 cols x 3 rows
            *reinterpret_cast<f32x2*>(&ovl[0 * G4H + cc0]) = a0;
            *reinterpret_cast<f32x2*>(&ovl[1 * G4H + cc0]) = a1;
            *reinterpret_cast<f32x2*>(&ovl[2 * G4H + cc0]) = a2;
            __syncthreads();  // T2: zfin ready

            // ---- P2: z + xz -> gates -> cell update -> h(t+1) fp16 into hpk
            {
                float z[4];
#pragma unroll
                for (int gg = 0; gg < 4; ++gg) {
                    float zv = ovl[rA * G4H + gg * 256 + uA];
                    const h2 xp = as_h2(xzu[(tc * 3 + rA) * 512 + gg * 128 + (uA >> 1)]);
                    zv += (uA & 1) ? (float)xp[1] : (float)xp[0];
                    z[gg] = zv;
                }
                cstA = sigmf(z[1]) * cstA + sigmf(z[0]) * tanhf_fast(z[2]);
                const float hn = sigmf(z[3]) * tanhf_fast(cstA);
                ((_Float16*)hpk)[((uA >> 1) * 4 + rA) * 2 + (uA & 1)] = (_Float16)hn;
            }
            if (tid < 256) {
                float z[4];
#pragma unroll
                for (int gg = 0; gg < 4; ++gg) {
                    float zv = ovl[2 * G4H + gg * 256 + tid];
                    const h2 xp = as_h2(xzu[(tc * 3 + 2) * 512 + gg * 128 + (tid >> 1)]);
                    zv += (tid & 1) ? (float)xp[1] : (float)xp[0];
                    z[gg] = zv;
                }
                cstB = sigmf(z[1]) * cstB + sigmf(z[0]) * tanhf_fast(z[2]);
                const float hn = sigmf(z[3]) * tanhf_fast(cstB);
                ((_Float16*)hpk)[((tid >> 1) * 4 + 2) * 2 + (tid & 1)] = (_Float16)hn;
            }
            // no barrier: next T1 (or A0) orders hpk writes vs reads
        }
    }
    __syncthreads();

    // ---- Fused head: out[row] = relu(h@w1+b1)@w2 + b2 (h fp16 from hpk)
    if (tid < 300) {
        const int r = tid / 100, j = tid - r * 100;
        if (r < nval) {
            float a = b1[j];
            const _Float16* hph = (const _Float16*)hpk;
#pragma unroll 8
            for (int k = 0; k < HDIM; ++k)
                a += (float)hph[((k >> 1) * 4 + r) * 2 + (k & 1)] * w1[k * 100 + j];
            hid[r][j] = fmaxf(a, 0.f);
        }
    }
    __syncthreads();
    if (tid < 3 && tid < nval) {
        float v = b2[0];
#pragma unroll 4
        for (int j = 0; j < 100; ++j) v += hid[tid][j] * w2[j];
        out[base + tid] = v;
    }
}

extern "C" void kernel_launch(void* const* d_in, const int* in_sizes, int n_in,
                              void* d_out, int out_size, void* d_ws, size_t ws_size,
                              hipStream_t stream)
{
    const float* x    = (const float*)d_in[0];
    const float* kern = (const float*)d_in[1];
    const float* rker = (const float*)d_in[2];
    const float* w1   = (const float*)d_in[3];
    const float* b1   = (const float*)d_in[4];
    const float* w2   = (const float*)d_in[5];
    const float* b2   = (const float*)d_in[6];
    float* out = (float*)d_out;

    u32* wpk = (u32*)d_ws;  // 768 KB

    conv_wpk<<<dim3(768), dim3(256), 0, stream>>>(kern, rker, wpk);
    lstm_chunk<<<dim3(NB), dim3(512), 0, stream>>>(x, wpk, w1, b1, w2, b2, out);
}